// Round 1
// 465.894 us; speedup vs baseline: 1.1171x; 1.1171x over previous
//
#include <hip/hip_runtime.h>

// Problem: out = (phi(Q) @ KV) / (phi(Q) @ Z + eps), phi = elu+1
// Q: [128 bh][4096 l][128 d] fp32, KV: [128 bh][128 d][128 e] fp32, Z: [128 bh][128 d]
// out fp32 same layout as Q.
//
// Strategy: bf16 MFMA numerator (A=bf16(phi), B=KV split hi/lo bf16 -> 2 passes),
// fp64-accumulated denominator with fp64-exp refinement for |den| < 0.01 rows.
// KV pre-swizzled into MFMA B-fragment order in d_ws (needs 8 MiB).
//
// R1 changes (theory: L3-BW/latency-bound on redundant B-table reads):
//  - wave-specialized n0: each wave owns cols {2w,2w+1}*16, holds its 16 B-frags in
//    VGPRs for the whole block -> 4x less table read traffic (256KB -> 64KB/block)
//  - XCD-chunked bijective block swizzle: same-bh blocks contiguous per XCD so the
//    64KB table stays L2-resident (old grid scattered all 128 bh across XCDs -> L3)
//  - B-frag loads issued before the barriers: latency hidden under phase-1 drain

#define BH   128
#define LQ   4096
#define DD   128
#define TL   128     // rows per block
#define APAD 136     // 128 + 8 bf16 pad -> 272 B row stride, conflict-free-ish
#define EPS  1e-6

typedef __attribute__((ext_vector_type(8))) short bf16x8;
typedef __attribute__((ext_vector_type(4))) float f32x4;

__device__ __forceinline__ unsigned short f2bf_rne(float f){
  unsigned u = __float_as_uint(f);
  u += 0x7FFFu + ((u >> 16) & 1u);
  return (unsigned short)(u >> 16);
}
__device__ __forceinline__ float bf2f(unsigned short h){
  return __uint_as_float(((unsigned)h) << 16);
}

// ---------------- pre-kernel: swizzle KV into B-fragment order -----------------
// frag (bh, n0, kk): lane holds B[k = kk*32 + (lane>>4)*8 + j][e = n0*16 + (lane&15)]
// table element offset = (((bh*8 + n0)*4 + kk)*64 + lane)*8 + j
__global__ __launch_bounds__(256) void prep_b(const float* __restrict__ KV,
                                              unsigned short* __restrict__ Bhi,
                                              unsigned short* __restrict__ Blo){
  int flat = blockIdx.x * 256 + threadIdx.x;   // 0..262143
  int lane = flat & 63;
  int kk   = (flat >> 6) & 3;
  int n0   = (flat >> 8) & 7;
  int bh   = flat >> 11;
  int e  = n0 * 16 + (lane & 15);
  int kb = kk * 32 + (lane >> 4) * 8;
  const float* src = KV + (size_t)bh * DD * DD + (size_t)kb * DD + e;
  unsigned h[8], l[8];
  #pragma unroll
  for (int j = 0; j < 8; j++){
    float v = src[(size_t)j * DD];
    unsigned short hh = f2bf_rne(v);
    h[j] = hh;
    l[j] = f2bf_rne(v - bf2f(hh));
  }
  uint4 hv, lv;
  hv.x = h[0] | (h[1] << 16); hv.y = h[2] | (h[3] << 16);
  hv.z = h[4] | (h[5] << 16); hv.w = h[6] | (h[7] << 16);
  lv.x = l[0] | (l[1] << 16); lv.y = l[2] | (l[3] << 16);
  lv.z = l[4] | (l[5] << 16); lv.w = l[6] | (l[7] << 16);
  size_t o = (size_t)flat * 8;
  *(uint4*)(Bhi + o) = hv;
  *(uint4*)(Blo + o) = lv;
}

// ---------------- main kernel -----------------
__global__ __launch_bounds__(256, 3) void kat_main(const float* __restrict__ Q,
                                                   const float* __restrict__ Z,
                                                   const unsigned short* __restrict__ Bhi,
                                                   const unsigned short* __restrict__ Blo,
                                                   float* __restrict__ Out){
  __shared__ unsigned short Ahi[TL * APAD];  // 34816 B
  __shared__ double sden[TL];
  __shared__ __align__(16) float srden[TL];
  __shared__ int    snf;
  __shared__ int    slist[TL];

  // XCD-chunked bijective swizzle (nwg=4096, 8 XCDs, 512 wg/XCD).
  // Consecutive blockIdx round-robin XCDs; chunking makes each XCD sweep a
  // contiguous wg range -> co-resident blocks on an XCD share bh -> tables L2-hit.
  const int flat = blockIdx.x;                          // 0..4095
  const int wg   = (flat & 7) * ((BH * (LQ / TL)) / 8) + (flat >> 3);
  const int bh = wg >> 5;                               // 32 L-tiles per bh
  const int lt = wg & 31;
  const int t  = threadIdx.x;
  const size_t qbase = ((size_t)bh * LQ + (size_t)lt * TL) * DD;

  if (t == 0) snf = 0;

  // ---- phase 1: stream Q, phi, bf16 A-tile to LDS, fp64 denominators ----
  const int c4 = t & 31;                        // float4 column index (same every i)
  const float4 z4 = *(const float4*)(Z + (size_t)bh * DD + c4 * 4);
  const double zz0 = z4.x, zz1 = z4.y, zz2 = z4.z, zz3 = z4.w;

  #pragma unroll 4
  for (int i = 0; i < 16; i++){
    int idx = t + 256 * i;
    int row = idx >> 5;                         // 32 consecutive lanes share a row
    const float4 q = *(const float4*)(Q + qbase + (size_t)row * DD + c4 * 4);
    float p0 = q.x > 0.f ? q.x + 1.f : expf(q.x);
    float p1 = q.y > 0.f ? q.y + 1.f : expf(q.y);
    float p2 = q.z > 0.f ? q.z + 1.f : expf(q.z);
    float p3 = q.w > 0.f ? q.w + 1.f : expf(q.w);
    unsigned h0 = f2bf_rne(p0), h1 = f2bf_rne(p1), h2 = f2bf_rne(p2), h3 = f2bf_rne(p3);
    uint2 pk; pk.x = h0 | (h1 << 16); pk.y = h2 | (h3 << 16);
    *(uint2*)&Ahi[row * APAD + c4 * 4] = pk;
    double part = (double)p0 * zz0 + (double)p1 * zz1 + (double)p2 * zz2 + (double)p3 * zz3;
    #pragma unroll
    for (int msk = 16; msk >= 1; msk >>= 1) part += __shfl_xor(part, msk, 64);
    if ((t & 31) == 0) sden[row] = part;
  }

  // ---- B fragments: wave w owns n0 in {2w, 2w+1}. Issue loads NOW (no
  // dependence on phase 1) so L2/L3 latency hides under the barrier drain. ----
  const int lane = t & 63;
  const int w    = t >> 6;
  bf16x8 bhf[2][4], blf[2][4];
  {
    const size_t fb0 = (size_t)bh * (DD * DD) + (size_t)lane * 8;
    #pragma unroll
    for (int n = 0; n < 2; n++){
      const size_t fb = fb0 + (size_t)(2 * w + n) * 2048;   // n0 stride = 4 kk * 512
      #pragma unroll
      for (int kk = 0; kk < 4; kk++){
        bhf[n][kk] = *(const bf16x8*)(Bhi + fb + kk * 512);
        blf[n][kk] = *(const bf16x8*)(Blo + fb + kk * 512);
      }
    }
  }
  __syncthreads();

  // ---- flag near-singular denominators (rare) ----
  if (t < TL){
    if (fabs(sden[t]) < 0.01){
      int p = atomicAdd(&snf, 1);
      slist[p] = t;
    }
  }
  __syncthreads();
  int nf = snf;
  if (nf > 0 && t < 64){
    // wave 0 recomputes flagged rows in full fp64 (exp in double)
    for (int f = 0; f < nf; f++){
      int r = slist[f];
      const float* qr = Q + qbase + (size_t)r * DD;
      int d0 = t * 2;
      double s = 0.0;
      #pragma unroll
      for (int u = 0; u < 2; u++){
        float qv = qr[d0 + u];
        double qphi = (qv > 0.f) ? ((double)qv + 1.0) : exp((double)qv);
        s += qphi * (double)Z[(size_t)bh * DD + d0 + u];
      }
      #pragma unroll
      for (int msk = 32; msk >= 1; msk >>= 1) s += __shfl_xor(s, msk, 64);
      if (t == 0) sden[r] = s;
    }
  }
  __syncthreads();
  if (t < TL) srden[t] = (float)(1.0 / (sden[t] + EPS));
  __syncthreads();

  // ---- phase 2: MFMA. Wave w covers cols 32w..32w+31 for ALL 128 rows ----
  const int m    = lane & 15;
  const int quad = lane >> 4;

  #pragma unroll 2
  for (int rg = 0; rg < 8; rg++){
    bf16x8 afr[4];
    #pragma unroll
    for (int kk = 0; kk < 4; kk++)
      afr[kk] = *(const bf16x8*)&Ahi[(rg * 16 + m) * APAD + kk * 32 + quad * 8];
    const f32x4 rdv = *(const f32x4*)&srden[rg * 16 + quad * 4];  // broadcast per 16-lane group

    f32x4 acc[2][2];   // [n0][hi/lo] -> 4 independent MFMA chains of depth 4
    #pragma unroll
    for (int n = 0; n < 2; n++){
      acc[n][0] = (f32x4){0.f, 0.f, 0.f, 0.f};
      acc[n][1] = (f32x4){0.f, 0.f, 0.f, 0.f};
    }
    #pragma unroll
    for (int kk = 0; kk < 4; kk++){
      acc[0][0] = __builtin_amdgcn_mfma_f32_16x16x32_bf16(afr[kk], bhf[0][kk], acc[0][0], 0, 0, 0);
      acc[1][0] = __builtin_amdgcn_mfma_f32_16x16x32_bf16(afr[kk], bhf[1][kk], acc[1][0], 0, 0, 0);
      acc[0][1] = __builtin_amdgcn_mfma_f32_16x16x32_bf16(afr[kk], blf[0][kk], acc[0][1], 0, 0, 0);
      acc[1][1] = __builtin_amdgcn_mfma_f32_16x16x32_bf16(afr[kk], blf[1][kk], acc[1][1], 0, 0, 0);
    }
    // C/D layout: col = lane&15, row = quad*4 + reg  [m89]
    #pragma unroll
    for (int n = 0; n < 2; n++){
      f32x4 s = acc[n][0] + acc[n][1];
      float* op = Out + qbase + (size_t)(rg * 16 + quad * 4) * DD + (2 * w + n) * 16 + m;
      #pragma unroll
      for (int reg = 0; reg < 4; reg++)
        op[(size_t)reg * DD] = s[reg] * rdv[reg];
    }
  }
}

extern "C" void kernel_launch(void* const* d_in, const int* in_sizes, int n_in,
                              void* d_out, int out_size, void* d_ws, size_t ws_size,
                              hipStream_t stream){
  const float* Q  = (const float*)d_in[0];
  const float* KV = (const float*)d_in[1];
  const float* Z  = (const float*)d_in[2];
  unsigned short* Bhi = (unsigned short*)d_ws;              // 4 MiB
  unsigned short* Blo = Bhi + (size_t)BH * DD * DD;         // 4 MiB (ws needs 8 MiB)

  prep_b<<<1024, 256, 0, stream>>>(KV, Bhi, Blo);
  kat_main<<<dim3(BH * (LQ / TL)), 256, 0, stream>>>(Q, Z, Bhi, Blo, (float*)d_out);
}